// Round 11
// baseline (154.566 us; speedup 1.0000x reference)
//
#include <hip/hip_runtime.h>

#pragma clang fp contract(off)

// ChamferLoss: BS=4, N=M=8192, D=3
// out: [0] min over gts per pred [4][8192]; [1] min over preds per gt;
//      [2] argmin gts per pred (float); [3] argmin preds per gt (float)
//
// Bit-exact numpy fp32 emulation (PASS rounds 6-10), NO FMA anywhere
// (pragma contract(off); ROCm __f*_rn do NOT block contraction):
//   rr = ((x*x + y*y) + z*z)         ascending
//   zz = ((x0*y0 + x1*y1) + x2*y2)   ascending, no FMA
//   P  = ((rr_n + rr_m) - (2*zz))    left-to-right; *2 exact
//
// Round 11: FUSED symmetric kernel — each P[n,m] computed ONCE, feeding both
// the row-min (over m, per gt) and col-min (over n, per pred). Halves the
// pair-evals (537M -> 268M). v_pk_f32 gives no fp32 exec-rate gain on CDNA4
// (157.3 TF peak == 32 lanes x 2 FLOP), so the only lever is fewer ops.
//   - block = 64 gt rows x all 8192 preds; lane owns 8 gts in regs
//     (row accs lane-local); wave owns a 512-pred window.
//   - preds staged ONCE in 128KB LDS (pair-interleaved quads), 1 barrier.
//   - col-min over the block's 64 gts closed per 16-pred chunk by an
//     intra-wave shfl_xor butterfly (no barrier), then folded cross-block
//     via atomicMin on sortable u64 key (monotone_f32<<32 | n_idx):
//     order-independent => deterministic; lex (v,idx) == numpy
//     first-occurrence argmin (each entry computed once => v bit-unique).

#define BS    4
#define NPTS  8192

typedef float f32x4 __attribute__((ext_vector_type(4)));

__global__ __launch_bounds__(1024, 4)
void chamfer_fused(const float* __restrict__ preds,
                   const float* __restrict__ gts,
                   float* __restrict__ out,
                   unsigned long long* __restrict__ colkey)
{
#pragma clang fp contract(off)
    const int b    = blockIdx.y;
    const int n0   = blockIdx.x * 64;          // gt stripe base
    const int t    = threadIdx.x;
    const int w    = t >> 6;                   // wave 0..15
    const int lane = t & 63;
    const int ng   = lane >> 3;                // 0..7 : gt sub-group
    const int mg   = lane & 7;                 // 0..7 : pred sub-group

    const float* mb = preds + (size_t)b * NPTS * 3;
    const float* gb = gts   + (size_t)b * NPTS * 3;

    // LDS: pred tile, pair-interleaved quads:
    //   xy quad p = (x_{2p}, x_{2p+1}, y_{2p}, y_{2p+1})
    //   zr quad p = (z_{2p}, z_{2p+1}, rr_{2p}, rr_{2p+1})
    __shared__ alignas(16) float smem[32768];          // 128 KB
    __shared__ float rs_v[16 * 64];                    // row merge scratch
    __shared__ int   rs_i[16 * 64];
    float* xyf = smem;
    float* zrf = smem + 16384;
    const f32x4* shxy4 = (const f32x4*)smem;
    const f32x4* shzr4 = (const f32x4*)(smem + 16384);

    // ---- stage all 8192 preds (8 points/thread), rr ascending no-FMA
    for (int k = 0; k < 8; ++k) {
        const int p = k * 1024 + t;
        const float x = mb[p * 3 + 0];
        const float y = mb[p * 3 + 1];
        const float z = mb[p * 3 + 2];
        const float a0 = x * x;
        const float a1 = y * y;
        const float a2 = z * z;
        const float rr = (a0 + a1) + a2;
        const int pr = p >> 1, h = p & 1;
        xyf[pr * 4 + h]     = x;
        xyf[pr * 4 + 2 + h] = y;
        zrf[pr * 4 + h]     = z;
        zrf[pr * 4 + 2 + h] = rr;
    }

    // ---- this lane's 8 gt points in registers
    const int nbase = n0 + ng * 8;
    float qx[8], qy[8], qz[8], rq[8];
#pragma unroll
    for (int rn = 0; rn < 8; ++rn) {
        const int n = nbase + rn;
        const float x = gb[n * 3 + 0];
        const float y = gb[n * 3 + 1];
        const float z = gb[n * 3 + 2];
        qx[rn] = x; qy[rn] = y; qz[rn] = z;
        const float a0 = x * x;
        const float a1 = y * y;
        const float a2 = z * z;
        rq[rn] = (a0 + a1) + a2;
    }

    float rowv[8];
    int   rowi[8];
#pragma unroll
    for (int rn = 0; rn < 8; ++rn) { rowv[rn] = 3.0e38f; rowi[rn] = 0; }

    __syncthreads();

    // ---- main loop: wave w owns preds [w*512, (w+1)*512), 32 chunks of 16
    const int ppbase = w * 256;
    const unsigned long long* dummy = colkey;  (void)dummy;
    for (int c = 0; c < 32; ++c) {
        const int pp = ppbase + c * 8 + mg;        // pair index
        const f32x4 axy = shxy4[pp];
        const f32x4 azr = shzr4[pp];
        const int m0 = pp * 2;
#pragma unroll
        for (int rm = 0; rm < 2; ++rm) {
            const float mx  = axy[rm];
            const float my  = axy[2 + rm];
            const float mz  = azr[rm];
            const float mrr = azr[2 + rm];
            const int   mi  = m0 + rm;
            float cv = 3.0e38f;
            int   ci = 0;
#pragma unroll
            for (int rn = 0; rn < 8; ++rn) {
                // zz ascending ((d0 + d1) + d2), no FMA
                const float p0  = mx * qx[rn];
                const float p1  = my * qy[rn];
                const float s01 = p0 + p1;
                const float p2  = mz * qz[rn];
                const float zz  = s01 + p2;
                // P = (rr_n + rr_m) - (2*zz)   (+ commutes bit-exactly)
                const float ts = mrr + rq[rn];
                const float wd = 2.0f * zz;
                const float v  = ts - wd;
                if (v < rowv[rn]) { rowv[rn] = v; rowi[rn] = mi; }
                if (v < cv)       { cv = v;       ci = rn; }
            }
            // column-min over this wave's 64 gts: butterfly over ng (stride 8)
            int cn = nbase + ci;
#pragma unroll
            for (int o = 8; o < 64; o <<= 1) {
                const float ov = __shfl_xor(cv, o);
                const int   on = __shfl_xor(cn, o);
                if (ov < cv || (ov == cv && on < cn)) { cv = ov; cn = on; }
            }
            if (ng == 0) {
                // sortable key: monotone u32 of cv, then n index (lex-min)
                const unsigned bits = __float_as_uint(cv);
                const unsigned s = (bits & 0x80000000u) ? ~bits
                                                        : (bits | 0x80000000u);
                const unsigned long long key =
                    ((unsigned long long)s << 32) | (unsigned)cn;
                atomicMin(&colkey[(size_t)b * NPTS + mi], key);
            }
        }
    }

    // ---- row outputs: merge over mg (shfl), then over 16 waves (LDS)
#pragma unroll
    for (int rn = 0; rn < 8; ++rn) {
        float cv = rowv[rn];
        int   cn = rowi[rn];
#pragma unroll
        for (int o = 1; o < 8; o <<= 1) {
            const float ov = __shfl_xor(cv, o);
            const int   on = __shfl_xor(cn, o);
            if (ov < cv || (ov == cv && on < cn)) { cv = ov; cn = on; }
        }
        if (mg == 0) {
            rs_v[w * 64 + ng * 8 + rn] = cv;
            rs_i[w * 64 + ng * 8 + rn] = cn;
        }
    }
    __syncthreads();
    if (t < 64) {
        float bv = rs_v[t];
        int   bi = rs_i[t];
        for (int ww = 1; ww < 16; ++ww) {
            const float v2 = rs_v[ww * 64 + t];
            const int   i2 = rs_i[ww * 64 + t];
            if (v2 < bv || (v2 == bv && i2 < bi)) { bv = v2; bi = i2; }
        }
        const int n = n0 + t;
        out[(size_t)(1) * BS * NPTS + (size_t)b * NPTS + n] = bv;       // out1
        out[(size_t)(3) * BS * NPTS + (size_t)b * NPTS + n] = (float)bi;// out3
    }
}

__global__ __launch_bounds__(256)
void chamfer_finalize(const unsigned long long* __restrict__ colkey,
                      float* __restrict__ out)
{
    const int i = blockIdx.x * 256 + threadIdx.x;   // b*8192 + m, 0..32767
    const unsigned long long k = colkey[i];
    const unsigned s   = (unsigned)(k >> 32);
    const unsigned idx = (unsigned)k;
    const unsigned bits = (s & 0x80000000u) ? (s ^ 0x80000000u) : ~s;
    out[i] = __uint_as_float(bits);                              // out0
    out[(size_t)(2) * BS * NPTS + i] = (float)idx;               // out2
}

// ---------- fallback (round-9 kernel, proven PASS @118us) ----------
#define CHUNK  1024
#define SPLITS 32
#define SLOTS  32
#define QT     8
#define QBLK   (SLOTS * QT)
#define ROWS   (CHUNK / SPLITS)

__global__ __launch_bounds__(1024, 4)
void chamfer_sep(const float* __restrict__ preds,
                 const float* __restrict__ gts,
                 float* __restrict__ out)
{
#pragma clang fp contract(off)
    const int dir   = blockIdx.z;
    const int b     = blockIdx.y;
    const int t     = threadIdx.x;
    const int slot  = t & (SLOTS - 1);
    const int split = t >> 5;
    const int qb    = blockIdx.x * QBLK;

    const float* qbase = (dir == 0 ? preds : gts) + (size_t)b * NPTS * 3;
    const float* rbase = (dir == 0 ? gts : preds) + (size_t)b * NPTS * 3;
    float* outv = out + (size_t)dir       * BS * NPTS + (size_t)b * NPTS;
    float* outi = out + (size_t)(2 + dir) * BS * NPTS + (size_t)b * NPTS;

    __shared__ float smem[12288];
    float (*sh)[4]        = (float (*)[4])smem;
    float *shv            = smem;
    unsigned short *shi16 = (unsigned short *)(smem + 8192);

    float qxv[QT], qyv[QT], qzv[QT], rqv[QT];
#pragma unroll
    for (int j = 0; j < QT; ++j) {
        const int q = qb + j * SLOTS + slot;
        const float x = qbase[(size_t)q * 3 + 0];
        const float y = qbase[(size_t)q * 3 + 1];
        const float z = qbase[(size_t)q * 3 + 2];
        qxv[j] = x; qyv[j] = y; qzv[j] = z;
        const float a0 = x * x, a1 = y * y, a2 = z * z;
        rqv[j] = (a0 + a1) + a2;
    }

    float bestv[QT]; int besti[QT];
#pragma unroll
    for (int j = 0; j < QT; ++j) { bestv[j] = 3.0e38f; besti[j] = 0; }

    for (int c = 0; c < NPTS / CHUNK; ++c) {
        __syncthreads();
        {
            const size_t n = (size_t)c * CHUNK + t;
            const float x = rbase[n * 3 + 0];
            const float y = rbase[n * 3 + 1];
            const float z = rbase[n * 3 + 2];
            sh[t][0] = x; sh[t][1] = y; sh[t][2] = z;
            const float a0 = x * x, a1 = y * y, a2 = z * z;
            sh[t][3] = (a0 + a1) + a2;
        }
        __syncthreads();
        const int row0 = split * ROWS;
#pragma unroll 4
        for (int k = 0; k < ROWS; ++k) {
            const int row = row0 + k;
            const float x = sh[row][0], y = sh[row][1];
            const float z = sh[row][2], rr = sh[row][3];
            const int idx = c * CHUNK + row;
#pragma unroll
            for (int j = 0; j < QT; ++j) {
                const float p0 = x * qxv[j];
                const float p1 = y * qyv[j];
                const float p2 = z * qzv[j];
                const float zz = (p0 + p1) + p2;
                const float ts = rr + rqv[j];
                const float wd = 2.0f * zz;
                const float v  = ts - wd;
                if (v < bestv[j]) { bestv[j] = v; besti[j] = idx; }
            }
        }
    }

    __syncthreads();
#pragma unroll
    for (int j = 0; j < QT; ++j) {
        shv  [split * QBLK + j * SLOTS + slot] = bestv[j];
        shi16[split * QBLK + j * SLOTS + slot] = (unsigned short)besti[j];
    }
    __syncthreads();
    const int qloc = t >> 2;
    const int sl   = t & 3;
    float bv = 3.0e38f; int bi = 0;
#pragma unroll
    for (int k = 0; k < SPLITS / 4; ++k) {
        const int s = sl + k * 4;
        const float v2 = shv[s * QBLK + qloc];
        const int   i2 = shi16[s * QBLK + qloc];
        if (v2 < bv || (v2 == bv && i2 < bi)) { bv = v2; bi = i2; }
    }
#pragma unroll
    for (int o = 1; o < 4; o <<= 1) {
        const float ov = __shfl_xor(bv, o);
        const int   oi = __shfl_xor(bi, o);
        if (ov < bv || (ov == bv && oi < bi)) { bv = ov; bi = oi; }
    }
    if (sl == 0) { outv[qb + qloc] = bv; outi[qb + qloc] = (float)bi; }
}

extern "C" void kernel_launch(void* const* d_in, const int* in_sizes, int n_in,
                              void* d_out, int out_size, void* d_ws, size_t ws_size,
                              hipStream_t stream)
{
    const float* preds = (const float*)d_in[0];  // [BS, M, 3]
    const float* gts   = (const float*)d_in[1];  // [BS, N, 3]
    float* out = (float*)d_out;

    const size_t need = (size_t)BS * NPTS * sizeof(unsigned long long); // 256 KB
    if (ws_size >= need) {
        hipMemsetAsync(d_ws, 0xFF, need, stream);   // keys = u64 max
        chamfer_fused<<<dim3(NPTS / 64, BS), 1024, 0, stream>>>(
            preds, gts, out, (unsigned long long*)d_ws);
        chamfer_finalize<<<dim3(BS * NPTS / 256), 256, 0, stream>>>(
            (const unsigned long long*)d_ws, out);
    } else {
        chamfer_sep<<<dim3(NPTS / QBLK, BS, 2), 1024, 0, stream>>>(preds, gts, out);
    }
}

// Round 12
// 149.967 us; speedup vs baseline: 1.0307x; 1.0307x over previous
//
#include <hip/hip_runtime.h>

#pragma clang fp contract(off)

// ChamferLoss: BS=4, N=M=8192, D=3
// Outputs (concatenated, float):
//   [0*32768 .. )  min over gts  for each pred   [BS, M]
//   [1*32768 .. )  min over preds for each gt    [BS, N]
//   [2*32768 .. )  argmin over gts  (as float)   [BS, M]
//   [3*32768 .. )  argmin over preds (as float)  [BS, N]
//
// Bit-exact numpy fp32 emulation (PASS rounds 6-11), NO FMA anywhere
// (pragma contract(off); ROCm __f*_rn do NOT block contraction):
//   rr = ((x*x + y*y) + z*z)           ascending
//   zz = ((x0*y0 + x1*y1) + x2*y2)     ascending, no FMA
//   P  = ((rr_n + rr_m) - (2*zz))      left-to-right; *2 exact
// P operand-symmetric => both reduction directions identical bits.
//
// Round 12: revert fused experiment (r11: reduction overhead tripled
// per-pair cost). r9 structure, PURE SCALAR floats — no ext_vector_type:
// f32x2 gave no exec-rate gain (CDNA4 fp32 peak = 32 lanes x 2 FLOP) but
// forced even-aligned VGPR pairs -> v_mov marshalling ~4-5 inst/pair.
// QT=8, SLOTS=32 x SPLITS=32, 1024 thr, 4 waves/SIMD, 256 blocks.

#define BS     4
#define NPTS   8192
#define CHUNK  1024
#define BLOCK  1024
#define SPLITS 32
#define SLOTS  32                 // query slots per block
#define QT     8                  // queries per thread
#define QBLK   (SLOTS * QT)       // 256 queries per block
#define ROWS   (CHUNK / SPLITS)   // 32 candidate rows per chunk per split

__global__ __launch_bounds__(BLOCK, 4)
void chamfer_kernel(const float* __restrict__ preds,
                    const float* __restrict__ gts,
                    float* __restrict__ out)
{
#pragma clang fp contract(off)
    const int dir   = blockIdx.z;  // 0: per-pred min over gts, 1: per-gt min over preds
    const int b     = blockIdx.y;
    const int t     = threadIdx.x;
    const int slot  = t & (SLOTS - 1);   // query slot within block
    const int split = t >> 5;            // candidate split
    const int qb    = blockIdx.x * QBLK;

    const float* qbase = (dir == 0 ? preds : gts) + (size_t)b * NPTS * 3;
    const float* rbase = (dir == 0 ? gts : preds) + (size_t)b * NPTS * 3;
    float* outv = out + (size_t)dir       * BS * NPTS + (size_t)b * NPTS;
    float* outi = out + (size_t)(2 + dir) * BS * NPTS + (size_t)b * NPTS;

    // 48KB shared: [0,16K) candidate tile; after final barrier reused as
    // merge scratch: shv [SPLITS][QBLK] f32 + shi16 [SPLITS][QBLK] u16
    __shared__ alignas(16) float smem[12288];
    float (*sh)[4]        = (float (*)[4])smem;                  // [CHUNK][4]
    float *shv            = smem;                                // [SPLITS*QBLK]
    unsigned short *shi16 = (unsigned short *)(smem + 8192);

    // QT=8 query points, pure scalar regs
    float qx[QT], qy[QT], qz[QT], rq[QT];
#pragma unroll
    for (int j = 0; j < QT; ++j) {
        const int q = qb + j * SLOTS + slot;
        const float x = qbase[(size_t)q * 3 + 0];
        const float y = qbase[(size_t)q * 3 + 1];
        const float z = qbase[(size_t)q * 3 + 2];
        qx[j] = x; qy[j] = y; qz[j] = z;
        const float a0 = x * x;
        const float a1 = y * y;
        const float a2 = z * z;
        rq[j] = (a0 + a1) + a2;     // ascending, no FMA
    }

    float bestv[QT];
    int   besti[QT];
#pragma unroll
    for (int j = 0; j < QT; ++j) { bestv[j] = 3.0e38f; besti[j] = 0; }

    const int nchunks = NPTS / CHUNK;
    for (int c = 0; c < nchunks; ++c) {
        __syncthreads();
        {   // stage: each of 1024 threads loads one point
            const size_t n = (size_t)c * CHUNK + t;
            const float x = rbase[n * 3 + 0];
            const float y = rbase[n * 3 + 1];
            const float z = rbase[n * 3 + 2];
            sh[t][0] = x;
            sh[t][1] = y;
            sh[t][2] = z;
            const float a0 = x * x;
            const float a1 = y * y;
            const float a2 = z * z;
            sh[t][3] = (a0 + a1) + a2;     // ascending, no FMA
        }
        __syncthreads();

        const int row0 = split * ROWS;
        const int idx0 = c * CHUNK + row0;
#pragma unroll 8
        for (int k = 0; k < ROWS; ++k) {
            const float x  = sh[row0 + k][0];
            const float y  = sh[row0 + k][1];
            const float z  = sh[row0 + k][2];
            const float rr = sh[row0 + k][3];
            const int idx = idx0 + k;
#pragma unroll
            for (int j = 0; j < QT; ++j) {
                // zz ascending ((d0 + d1) + d2), no FMA
                const float p0 = x * qx[j];
                const float p1 = y * qy[j];
                const float p2 = z * qz[j];
                const float zz = (p0 + p1) + p2;
                // P = (rr_n + rr_m) - (2*zz), left-to-right
                const float ts = rr + rq[j];
                const float w  = 2.0f * zz;
                const float v  = ts - w;
                if (v < bestv[j]) { bestv[j] = v; besti[j] = idx; }
            }
        }
    }

    // ---- Merge over splits; lex (v, idx) min == numpy first-occurrence argmin
    // (valid: v is bit-identical regardless of which split computes it)
    __syncthreads();   // all tile reads done; safe to overwrite smem
#pragma unroll
    for (int j = 0; j < QT; ++j) {
        shv  [split * QBLK + j * SLOTS + slot] = bestv[j];
        shi16[split * QBLK + j * SLOTS + slot] = (unsigned short)besti[j];
    }
    __syncthreads();

    // 4 threads per query: each lex-merges 8 splits, then shfl_xor reduce
    const int qloc = t >> 2;       // 0..255
    const int sl   = t & 3;
    float bv = 3.0e38f;
    int   bi = 0;
#pragma unroll
    for (int k = 0; k < SPLITS / 4; ++k) {
        const int s = sl + k * 4;
        const float v2 = shv[s * QBLK + qloc];
        const int   i2 = shi16[s * QBLK + qloc];
        if (v2 < bv || (v2 == bv && i2 < bi)) { bv = v2; bi = i2; }
    }
#pragma unroll
    for (int o = 1; o < 4; o <<= 1) {
        const float ov = __shfl_xor(bv, o);
        const int   oi = __shfl_xor(bi, o);
        if (ov < bv || (ov == bv && oi < bi)) { bv = ov; bi = oi; }
    }
    if (sl == 0) {
        outv[qb + qloc] = bv;
        outi[qb + qloc] = (float)bi;
    }
}

extern "C" void kernel_launch(void* const* d_in, const int* in_sizes, int n_in,
                              void* d_out, int out_size, void* d_ws, size_t ws_size,
                              hipStream_t stream)
{
    const float* preds = (const float*)d_in[0];  // [BS, M, 3]
    const float* gts   = (const float*)d_in[1];  // [BS, N, 3]
    // d_in[2] = mask, unused (matches reference)
    float* out = (float*)d_out;

    dim3 grid(NPTS / QBLK, BS, 2);   // 32 x 4 x 2 = 256 blocks of 1024
    dim3 block(BLOCK);
    chamfer_kernel<<<grid, block, 0, stream>>>(preds, gts, out);
}